// Round 1
// baseline (11284.007 us; speedup 1.0000x reference)
//
#include <hip/hip_runtime.h>

// 2-layer LSTM, H=256, T=256, B=512, I=2, + linear head (2 outputs).
// Strategy: one block per 4 batch elements (128 blocks x 512 threads),
// t-loop inside the kernel (no inter-block deps). Weights pre-transposed
// into d_ws for coalesced streaming from L2; h1/h2 in LDS; c in registers.

typedef float vf2 __attribute__((ext_vector_type(2)));
typedef float vf4 __attribute__((ext_vector_type(4)));

#define HSZ 256
#define TSTEPS 256
#define NB 4
#define NTHREADS 512

// ws layout (floats)
#define W1T_OFF 0                       // [256][1024]  W1t[k][j] = W_hh1[j][k]
#define W2T_OFF (256 * 1024)            // [512][1024]  k<256: W_ih2[j][k], else W_hh2[j][k-256]
#define WX_OFF  (W2T_OFF + 512 * 1024)  // [2][1024]    Wx[i][j] = W_ih1[j][i]
#define B1_OFF  (WX_OFF + 2 * 1024)     // [1024]       b_ih1 + b_hh1
#define B2_OFF  (B1_OFF + 1024)         // [1024]       b_ih2 + b_hh2
#define WS_FLOATS (B2_OFF + 1024)

__global__ void prep_kernel(const float* __restrict__ W_ih1,
                            const float* __restrict__ W_hh1,
                            const float* __restrict__ b_ih1,
                            const float* __restrict__ b_hh1,
                            const float* __restrict__ W_ih2,
                            const float* __restrict__ W_hh2,
                            const float* __restrict__ b_ih2,
                            const float* __restrict__ b_hh2,
                            float* __restrict__ ws) {
    const int stride = gridDim.x * blockDim.x;
    const int idx = blockIdx.x * blockDim.x + threadIdx.x;
    for (int i = idx; i < 256 * 1024; i += stride) {
        int k = i >> 10, j = i & 1023;
        ws[W1T_OFF + i] = W_hh1[j * HSZ + k];
    }
    for (int i = idx; i < 512 * 1024; i += stride) {
        int k = i >> 10, j = i & 1023;
        ws[W2T_OFF + i] = (k < 256) ? W_ih2[j * HSZ + k] : W_hh2[j * HSZ + (k - 256)];
    }
    for (int i = idx; i < 2 * 1024; i += stride) {
        int c = i >> 10, j = i & 1023;
        ws[WX_OFF + i] = W_ih1[j * 2 + c];
    }
    for (int i = idx; i < 1024; i += stride) {
        ws[B1_OFF + i] = b_ih1[i] + b_hh1[i];
        ws[B2_OFF + i] = b_ih2[i] + b_hh2[i];
    }
}

__device__ __forceinline__ float sig_(float x) {
    return 1.f / (1.f + __expf(-x));
}
__device__ __forceinline__ float tanh_(float x) {
    // 1 - 2/(e^{2x}+1); saturates cleanly (inf -> 1, -inf -> -1)
    return 1.f - 2.f / (__expf(2.f * x) + 1.f);
}

__global__ __launch_bounds__(NTHREADS) void lstm_kernel(
    const float* __restrict__ x,      // (512, 256, 2)
    const float* __restrict__ ws,
    const float* __restrict__ W_lin,  // (2, 256)
    const float* __restrict__ b_lin,  // (2,)
    float* __restrict__ out)          // (512, 256, 2)
{
    const int tid = threadIdx.x;
    const int b0 = blockIdx.x * NB;

    __shared__ float hbuf[NB][512];       // [b][k]: k<256 = h1, k>=256 = h2
    __shared__ float gbuf[4 * HSZ][NB];   // gate pre-activations [j][b]
    __shared__ float xs[NB][2];

    const float* __restrict__ W1t = ws + W1T_OFF;
    const float* __restrict__ W2t = ws + W2T_OFF;
    const int j0 = 2 * tid;

    // persistent per-thread constants
    const vf2 wx0 = *(const vf2*)(ws + WX_OFF + 0 * 1024 + j0);
    const vf2 wx1 = *(const vf2*)(ws + WX_OFF + 1 * 1024 + j0);
    const vf2 bias1 = *(const vf2*)(ws + B1_OFF + j0);
    const vf2 bias2 = *(const vf2*)(ws + B2_OFF + j0);

    // cell-update assignment: thread handles hidden ku for batches bA, bA+1
    const int ku = tid & 255;
    const int bA = (tid >> 8) * 2;  // 0 or 2
    float c1a = 0.f, c1b = 0.f, c2a = 0.f, c2b = 0.f;

    // output stage: wave w handles (batch = w>>1, out = w&1)
    const int wv = tid >> 6, lane = tid & 63;
    const int ob = wv >> 1, oo = wv & 1;
    float wl0 = W_lin[oo * 256 + lane];
    float wl1 = W_lin[oo * 256 + 64 + lane];
    float wl2 = W_lin[oo * 256 + 128 + lane];
    float wl3 = W_lin[oo * 256 + 192 + lane];
    const float blin = b_lin[oo];

    // zero initial h
    for (int i = tid; i < NB * 512; i += NTHREADS) ((float*)hbuf)[i] = 0.f;
    __syncthreads();

    for (int t = 0; t < TSTEPS; ++t) {
        // stage x_t for the 4 batch elements
        if (tid < NB * 2) {
            xs[tid >> 1][tid & 1] = x[(b0 + (tid >> 1)) * (TSTEPS * 2) + t * 2 + (tid & 1)];
        }
        __syncthreads();  // B1: x staged, h from prev step stable

        // ---------------- layer 1 gates ----------------
        vf2 acc0, acc1, acc2, acc3;
        {
            float x00 = xs[0][0], x01 = xs[0][1];
            float x10 = xs[1][0], x11 = xs[1][1];
            float x20 = xs[2][0], x21 = xs[2][1];
            float x30 = xs[3][0], x31 = xs[3][1];
            acc0 = bias1 + wx0 * x00 + wx1 * x01;
            acc1 = bias1 + wx0 * x10 + wx1 * x11;
            acc2 = bias1 + wx0 * x20 + wx1 * x21;
            acc3 = bias1 + wx0 * x30 + wx1 * x31;
        }
        {
            const float* wp = W1t + j0;
            #pragma unroll 2
            for (int k = 0; k < 256; k += 4) {
                vf4 h0 = *(const vf4*)&hbuf[0][k];
                vf4 h1 = *(const vf4*)&hbuf[1][k];
                vf4 h2 = *(const vf4*)&hbuf[2][k];
                vf4 h3 = *(const vf4*)&hbuf[3][k];
                #pragma unroll
                for (int kk = 0; kk < 4; ++kk) {
                    vf2 w = *(const vf2*)(wp + (k + kk) * 1024);
                    acc0 += w * h0[kk];
                    acc1 += w * h1[kk];
                    acc2 += w * h2[kk];
                    acc3 += w * h3[kk];
                }
            }
        }
        gbuf[j0][0] = acc0.x; gbuf[j0 + 1][0] = acc0.y;
        gbuf[j0][1] = acc1.x; gbuf[j0 + 1][1] = acc1.y;
        gbuf[j0][2] = acc2.x; gbuf[j0 + 1][2] = acc2.y;
        gbuf[j0][3] = acc3.x; gbuf[j0 + 1][3] = acc3.y;
        __syncthreads();  // B2: gates1 visible

        // ---------------- layer 1 cell update ----------------
        {
            float iA = gbuf[ku][bA],           iB = gbuf[ku][bA + 1];
            float fA = gbuf[HSZ + ku][bA],     fB = gbuf[HSZ + ku][bA + 1];
            float gA = gbuf[2 * HSZ + ku][bA], gB = gbuf[2 * HSZ + ku][bA + 1];
            float oA = gbuf[3 * HSZ + ku][bA], oB = gbuf[3 * HSZ + ku][bA + 1];
            c1a = sig_(fA) * c1a + sig_(iA) * tanh_(gA);
            c1b = sig_(fB) * c1b + sig_(iB) * tanh_(gB);
            hbuf[bA][ku]     = sig_(oA) * tanh_(c1a);
            hbuf[bA + 1][ku] = sig_(oB) * tanh_(c1b);
        }
        __syncthreads();  // B3: h1 ready, gbuf free

        // ---------------- layer 2 gates (K = 512 over [h1; h2]) ----------------
        acc0 = bias2; acc1 = bias2; acc2 = bias2; acc3 = bias2;
        {
            const float* wp = W2t + j0;
            #pragma unroll 2
            for (int k = 0; k < 512; k += 4) {
                vf4 h0 = *(const vf4*)&hbuf[0][k];
                vf4 h1 = *(const vf4*)&hbuf[1][k];
                vf4 h2 = *(const vf4*)&hbuf[2][k];
                vf4 h3 = *(const vf4*)&hbuf[3][k];
                #pragma unroll
                for (int kk = 0; kk < 4; ++kk) {
                    vf2 w = *(const vf2*)(wp + (k + kk) * 1024);
                    acc0 += w * h0[kk];
                    acc1 += w * h1[kk];
                    acc2 += w * h2[kk];
                    acc3 += w * h3[kk];
                }
            }
        }
        gbuf[j0][0] = acc0.x; gbuf[j0 + 1][0] = acc0.y;
        gbuf[j0][1] = acc1.x; gbuf[j0 + 1][1] = acc1.y;
        gbuf[j0][2] = acc2.x; gbuf[j0 + 1][2] = acc2.y;
        gbuf[j0][3] = acc3.x; gbuf[j0 + 1][3] = acc3.y;
        __syncthreads();  // B4: gates2 visible

        // ---------------- layer 2 cell update ----------------
        {
            float iA = gbuf[ku][bA],           iB = gbuf[ku][bA + 1];
            float fA = gbuf[HSZ + ku][bA],     fB = gbuf[HSZ + ku][bA + 1];
            float gA = gbuf[2 * HSZ + ku][bA], gB = gbuf[2 * HSZ + ku][bA + 1];
            float oA = gbuf[3 * HSZ + ku][bA], oB = gbuf[3 * HSZ + ku][bA + 1];
            c2a = sig_(fA) * c2a + sig_(iA) * tanh_(gA);
            c2b = sig_(fB) * c2b + sig_(iB) * tanh_(gB);
            hbuf[bA][256 + ku]     = sig_(oA) * tanh_(c2a);
            hbuf[bA + 1][256 + ku] = sig_(oB) * tanh_(c2b);
        }
        __syncthreads();  // B5: h2 ready

        // ---------------- output y = h2 @ W_lin.T + b_lin ----------------
        {
            float p = hbuf[ob][256 + lane] * wl0
                    + hbuf[ob][256 + 64 + lane] * wl1
                    + hbuf[ob][256 + 128 + lane] * wl2
                    + hbuf[ob][256 + 192 + lane] * wl3;
            #pragma unroll
            for (int m = 32; m >= 1; m >>= 1) p += __shfl_xor(p, m, 64);
            if (lane == 0) {
                out[(b0 + ob) * (TSTEPS * 2) + t * 2 + oo] = p + blin;
            }
        }
        // next-iteration B1 provides the barrier before h/x are touched again
    }
}

extern "C" void kernel_launch(void* const* d_in, const int* in_sizes, int n_in,
                              void* d_out, int out_size, void* d_ws, size_t ws_size,
                              hipStream_t stream) {
    const float* x     = (const float*)d_in[0];
    const float* W_ih1 = (const float*)d_in[1];
    const float* W_hh1 = (const float*)d_in[2];
    const float* b_ih1 = (const float*)d_in[3];
    const float* b_hh1 = (const float*)d_in[4];
    const float* W_ih2 = (const float*)d_in[5];
    const float* W_hh2 = (const float*)d_in[6];
    const float* b_ih2 = (const float*)d_in[7];
    const float* b_hh2 = (const float*)d_in[8];
    const float* W_lin = (const float*)d_in[9];
    const float* b_lin = (const float*)d_in[10];
    float* ws = (float*)d_ws;
    float* out = (float*)d_out;

    prep_kernel<<<192, 256, 0, stream>>>(W_ih1, W_hh1, b_ih1, b_hh1,
                                         W_ih2, W_hh2, b_ih2, b_hh2, ws);
    lstm_kernel<<<512 / NB, NTHREADS, 0, stream>>>(x, ws, W_lin, b_lin, out);
}